// Round 1
// baseline (440.587 us; speedup 1.0000x reference)
//
#include <hip/hip_runtime.h>

#define BATCH 16
#define CIN   1024
#define HID   256
#define HW    4096

typedef __attribute__((ext_vector_type(8))) short bf16x8;
typedef __attribute__((ext_vector_type(4))) float f32x4;

struct __align__(16) f4  { float v[4]; };
struct __align__(8)  us4 { unsigned short v[4]; };

__device__ __forceinline__ float bf2f(unsigned short u) {
  unsigned int x = ((unsigned int)u) << 16;
  return __builtin_bit_cast(float, x);
}
__device__ __forceinline__ unsigned short f2bf(float f) {
  unsigned int u = __builtin_bit_cast(unsigned int, f);
  u += 0x7fff + ((u >> 16) & 1);            // round-to-nearest-even
  return (unsigned short)(u >> 16);
}

// C[b][m][pix] = sum_k A[m][k] * B[b][k][pix] + bias[m]
// A: [256][KDIM] fp32 row-major. Bsrc: [16][KDIM][4096], fp32 (GEMM1) or bf16 (GEMM2).
// grid = 512 (16 b x 32 pixel-tiles of 128), block = 512 (8 waves), tile 256x128.
template<int KDIM, bool B_BF16, bool DO_CTX, bool DO_BN>
__global__ __launch_bounds__(512)
void gemm_kernel(const float* __restrict__ A, const void* __restrict__ Bsrc,
                 const float* __restrict__ bias, unsigned short* __restrict__ Cout,
                 float* __restrict__ ctx_sum, float* __restrict__ bn_sums)
{
  __shared__ unsigned short A_sh[256 * 64];   // [m][k] bf16, XOR-swizzled
  __shared__ unsigned short B_sh[128 * 64];   // [pix][k] bf16, XOR-swizzled
  __shared__ float ctx_lds[1024];
  __shared__ float bn_lds[512];

  const int tid  = threadIdx.x;
  const int lane = tid & 63;
  const int wv   = tid >> 6;
  const int wm   = wv >> 1, wn = wv & 1;      // wave grid 4(M) x 2(N), wave tile 64x64
  const int lr   = lane & 15, lg = lane >> 4;

  const int blk  = blockIdx.x;
  const int b    = blk >> 5;
  const int pix0 = (blk & 31) << 7;

  if (DO_CTX) { for (int i = tid; i < 1024; i += 512) ctx_lds[i] = 0.f; }
  if (DO_BN)  { if (tid < 512) bn_lds[tid] = 0.f; }
  if (DO_CTX || DO_BN) __syncthreads();

  f32x4 acc[4][4] = {};
  const int c4 = tid & 15, q = tid >> 4;

  for (int kt = 0; kt < KDIM / 64; ++kt) {
    const int kbase = kt * 64;
    // ---- stage A: 256x64 fp32 -> bf16, [m][k]
    #pragma unroll
    for (int i = 0; i < 8; ++i) {
      int f = i * 512 + tid;
      int m = f >> 4, kq = f & 15;
      f4 v = *(const f4*)(A + (size_t)m * KDIM + kbase + kq * 4);
      us4 w = { f2bf(v.v[0]), f2bf(v.v[1]), f2bf(v.v[2]), f2bf(v.v[3]) };
      int byte = m * 128 + ((kq * 8) ^ ((m & 7) << 4));
      *(us4*)((char*)A_sh + byte) = w;
    }
    // ---- stage B: 64(k) x 128(pix), transpose into [pix][k]
    if (!B_BF16) {
      const float* xb = (const float*)Bsrc;
      f4 rv[4];
      #pragma unroll
      for (int i = 0; i < 4; ++i) {
        int c = kbase + 4 * c4 + i;
        rv[i] = *(const f4*)(xb + ((size_t)b * KDIM + c) * HW + pix0 + 4 * q);
      }
      if (DO_CTX) {   // fused context-pool partial sums (each x element staged once)
        #pragma unroll
        for (int i = 0; i < 4; ++i) {
          float s = rv[i].v[0] + rv[i].v[1] + rv[i].v[2] + rv[i].v[3];
          s += __shfl_xor(s, 16, 64);
          s += __shfl_xor(s, 32, 64);
          if (lane < 16) atomicAdd(&ctx_lds[kbase + 4 * c4 + i], s);
        }
      }
      #pragma unroll
      for (int j = 0; j < 4; ++j) {
        int pix = 4 * q + j;
        us4 w = { f2bf(rv[0].v[j]), f2bf(rv[1].v[j]), f2bf(rv[2].v[j]), f2bf(rv[3].v[j]) };
        int byte = pix * 128 + ((8 * c4) ^ ((pix & 7) << 4));
        *(us4*)((char*)B_sh + byte) = w;
      }
    } else {
      const unsigned short* db = (const unsigned short*)Bsrc;
      us4 rv[4];
      #pragma unroll
      for (int i = 0; i < 4; ++i) {
        int c = kbase + 4 * c4 + i;
        rv[i] = *(const us4*)(db + ((size_t)b * KDIM + c) * HW + pix0 + 4 * q);
      }
      #pragma unroll
      for (int j = 0; j < 4; ++j) {
        int pix = 4 * q + j;
        us4 w = { rv[0].v[j], rv[1].v[j], rv[2].v[j], rv[3].v[j] };
        int byte = pix * 128 + ((8 * c4) ^ ((pix & 7) << 4));
        *(us4*)((char*)B_sh + byte) = w;
      }
    }
    __syncthreads();
    // ---- compute: 2 x 16 MFMA per wave per K-step
    #pragma unroll
    for (int kk = 0; kk < 2; ++kk) {
      bf16x8 af[4], bfr[4];
      #pragma unroll
      for (int mi = 0; mi < 4; ++mi) {
        int row  = wm * 64 + mi * 16 + lr;
        int byte = row * 128 + ((((kk << 2) | lg) ^ (row & 7)) << 4);
        af[mi] = *(const bf16x8*)((const char*)A_sh + byte);
      }
      #pragma unroll
      for (int ni = 0; ni < 4; ++ni) {
        int pr   = wn * 64 + ni * 16 + lr;
        int byte = pr * 128 + ((((kk << 2) | lg) ^ (pr & 7)) << 4);
        bfr[ni] = *(const bf16x8*)((const char*)B_sh + byte);
      }
      #pragma unroll
      for (int mi = 0; mi < 4; ++mi)
        #pragma unroll
        for (int ni = 0; ni < 4; ++ni)
          acc[mi][ni] = __builtin_amdgcn_mfma_f32_16x16x32_bf16(af[mi], bfr[ni], acc[mi][ni], 0, 0, 0);
    }
    __syncthreads();
  }

  // ---- epilogue: bias, bf16 store, optional BN partial stats
  #pragma unroll
  for (int mi = 0; mi < 4; ++mi) {
    #pragma unroll
    for (int r = 0; r < 4; ++r) {
      int o = wm * 64 + mi * 16 + lg * 4 + r;   // C/D: col=lane&15, row=(lane>>4)*4+reg
      float bo = bias[o];
      #pragma unroll
      for (int ni = 0; ni < 4; ++ni) {
        int pix = pix0 + wn * 64 + ni * 16 + lr;
        float val = acc[mi][ni][r] + bo;
        Cout[((size_t)(b * HID + o)) * HW + pix] = f2bf(val);
        if (DO_BN) {
          float s = val, s2 = val * val;
          #pragma unroll
          for (int msk = 1; msk < 16; msk <<= 1) {
            s  += __shfl_xor(s,  msk, 64);
            s2 += __shfl_xor(s2, msk, 64);
          }
          if (lr == 0) { atomicAdd(&bn_lds[o], s); atomicAdd(&bn_lds[256 + o], s2); }
        }
      }
    }
  }
  if (DO_CTX || DO_BN) __syncthreads();
  if (DO_CTX) {
    for (int e = tid; e < 1024; e += 512)
      atomicAdd(&ctx_sum[(size_t)b * 1024 + e], ctx_lds[e]);
  }
  if (DO_BN) {
    if (tid < 512) atomicAdd(&bn_sums[tid], bn_lds[tid]);
  }
}

// tiny MLP: ctx = relu(mean@ctx_w^T+b) -> hddn = relu(ctx@kg_w1^T+b) -> kernels
__global__ __launch_bounds__(256)
void mlp_kernel(const float* __restrict__ ctx_sum,
                const float* __restrict__ ctx_w, const float* __restrict__ ctx_b,
                const float* __restrict__ kg_w1, const float* __restrict__ kg_b1,
                const float* __restrict__ kg_w2, const float* __restrict__ kg_b2,
                float* __restrict__ kern_out)
{
  __shared__ float mean_s[1024];
  __shared__ float ctx_s[256];
  __shared__ float hdn_s[512];
  const int b = blockIdx.x;
  const int tid = threadIdx.x, lane = tid & 63, wv = tid >> 6;

  #pragma unroll
  for (int i = 0; i < 4; ++i)
    mean_s[tid + i * 256] = ctx_sum[(size_t)b * 1024 + tid + i * 256] * (1.f / 4096.f);
  __syncthreads();

  for (int o = wv * 64; o < wv * 64 + 64; ++o) {
    float p = 0.f;
    #pragma unroll
    for (int k = 0; k < 16; ++k) { int c = lane + k * 64; p += mean_s[c] * ctx_w[(size_t)o * 1024 + c]; }
    #pragma unroll
    for (int m = 1; m < 64; m <<= 1) p += __shfl_xor(p, m, 64);
    if (lane == 0) ctx_s[o] = fmaxf(p + ctx_b[o], 0.f);
  }
  __syncthreads();

  for (int j = wv * 128; j < wv * 128 + 128; ++j) {
    float p = 0.f;
    #pragma unroll
    for (int k = 0; k < 4; ++k) { int c = lane + k * 64; p += ctx_s[c] * kg_w1[(size_t)j * 256 + c]; }
    #pragma unroll
    for (int m = 1; m < 64; m <<= 1) p += __shfl_xor(p, m, 64);
    if (lane == 0) hdn_s[j] = fmaxf(p + kg_b1[j], 0.f);
  }
  __syncthreads();

  for (int j = wv; j < 72; j += 4) {
    float p = 0.f;
    #pragma unroll
    for (int k = 0; k < 8; ++k) { int c = lane + k * 64; p += hdn_s[c] * kg_w2[(size_t)j * 512 + c]; }
    #pragma unroll
    for (int m = 1; m < 64; m <<= 1) p += __shfl_xor(p, m, 64);
    if (lane == 0) kern_out[b * 72 + j] = p + kg_b2[j];
  }
}

// per-sample per-group depthwise 3x3, padding=1 (cross-correlation, no flip)
__global__ __launch_bounds__(256)
void dwconv_kernel(const unsigned short* __restrict__ xt, const float* __restrict__ kern,
                   unsigned short* __restrict__ dw)
{
  const int b  = blockIdx.x >> 8;
  const int ch = blockIdx.x & 255;
  const int g  = ch >> 5;                      // CPG = 32
  __shared__ float kf[9];
  if (threadIdx.x < 9) kf[threadIdx.x] = kern[b * 72 + g * 9 + threadIdx.x];
  __syncthreads();
  const unsigned short* xp = xt + ((size_t)(b * HID + ch) << 12);
  unsigned short*       dp = dw + ((size_t)(b * HID + ch) << 12);
  #pragma unroll 4
  for (int i = 0; i < 16; ++i) {
    int p = (i << 8) + threadIdx.x;
    int h = p >> 6, wc = p & 63;
    float a = 0.f;
    #pragma unroll
    for (int ky = 0; ky < 3; ++ky) {
      int hh = h + ky - 1;
      if ((unsigned)hh < 64u) {
        #pragma unroll
        for (int kx = 0; kx < 3; ++kx) {
          int ww = wc + kx - 1;
          float xv = ((unsigned)ww < 64u) ? bf2f(xp[(hh << 6) + ww]) : 0.f;
          a += xv * kf[ky * 3 + kx];
        }
      }
    }
    dp[p] = f2bf(a);
  }
}

__global__ void bn_finalize_kernel(const float* __restrict__ bn_sums,
                                   const float* __restrict__ gamma, const float* __restrict__ beta,
                                   float* __restrict__ scale, float* __restrict__ shift)
{
  int t = threadIdx.x;
  if (t < 256) {
    const float inv_n = 1.f / 65536.f;          // B*H*W
    float m  = bn_sums[t] * inv_n;
    float v  = bn_sums[256 + t] * inv_n - m * m;
    float sc = gamma[t] * rsqrtf(v + 1e-5f);
    scale[t] = sc;
    shift[t] = beta[t] - m * sc;
  }
}

// out = xt + scale[o]*out_trans + shift[o]   (fp32 store)
__global__ __launch_bounds__(256)
void final_kernel(const unsigned short* __restrict__ xt, const unsigned short* __restrict__ ot,
                  const float* __restrict__ scale, const float* __restrict__ shift,
                  float* __restrict__ out)
{
  int g = blockIdx.x * 256 + threadIdx.x;       // group of 4 elements
  const int stride = 4096 * 256;
  #pragma unroll
  for (int it = 0; it < 4; ++it, g += stride) {
    int o = (g >> 10) & 255;
    us4 a = ((const us4*)xt)[g];
    us4 c = ((const us4*)ot)[g];
    float s = scale[o], h = shift[o];
    f4 r;
    #pragma unroll
    for (int j = 0; j < 4; ++j) r.v[j] = bf2f(a.v[j]) + s * bf2f(c.v[j]) + h;
    *(f4*)(out + (size_t)g * 4) = r;
  }
}

extern "C" void kernel_launch(void* const* d_in, const int* in_sizes, int n_in,
                              void* d_out, int out_size, void* d_ws, size_t ws_size,
                              hipStream_t stream)
{
  const float* x     = (const float*)d_in[0];
  const float* ctx_w = (const float*)d_in[1];
  const float* ctx_b = (const float*)d_in[2];
  const float* kg_w1 = (const float*)d_in[3];
  const float* kg_b1 = (const float*)d_in[4];
  const float* kg_w2 = (const float*)d_in[5];
  const float* kg_b2 = (const float*)d_in[6];
  const float* in_w  = (const float*)d_in[7];
  const float* in_b  = (const float*)d_in[8];
  const float* out_w = (const float*)d_in[9];
  const float* out_b = (const float*)d_in[10];
  const float* gamma = (const float*)d_in[11];
  const float* beta  = (const float*)d_in[12];
  float* out = (float*)d_out;

  char* ws = (char*)d_ws;
  unsigned short* xt  = (unsigned short*)ws;                 // 32 MiB bf16 xt
  unsigned short* dwb = (unsigned short*)(ws + 33554432);    // 32 MiB bf16 dw, aliased by out_trans
  float* ctx_sum = (float*)(ws + 67108864);                  // [16][1024]
  float* bn_sums = ctx_sum + 16384;                          // [512] (sum | sumsq)
  float* kern    = bn_sums + 512;                            // [16][72]
  float* scale   = kern + 1152;                              // [256]
  float* shift   = scale + 256;                              // [256]

  hipMemsetAsync(ctx_sum, 0, (16384 + 512) * sizeof(float), stream);

  gemm_kernel<1024, false, true,  false><<<512, 512, 0, stream>>>(in_w,  x,   in_b,  xt,  ctx_sum, nullptr);
  mlp_kernel<<<16, 256, 0, stream>>>(ctx_sum, ctx_w, ctx_b, kg_w1, kg_b1, kg_w2, kg_b2, kern);
  dwconv_kernel<<<4096, 256, 0, stream>>>(xt, kern, dwb);
  gemm_kernel<256,  true,  false, true ><<<512, 512, 0, stream>>>(out_w, dwb, out_b, dwb, nullptr, bn_sums);
  bn_finalize_kernel<<<1, 256, 0, stream>>>(bn_sums, gamma, beta, scale, shift);
  final_kernel<<<4096, 256, 0, stream>>>(xt, dwb, scale, shift, out);
}

// Round 2
// 289.108 us; speedup vs baseline: 1.5240x; 1.5240x over previous
//
#include <hip/hip_runtime.h>

#define BATCH 16
#define CIN   1024
#define HID   256
#define HW    4096

typedef __attribute__((ext_vector_type(8))) short bf16x8;
typedef __attribute__((ext_vector_type(4))) float f32x4;

struct __align__(16) f4  { float v[4]; };
struct __align__(8)  us4 { unsigned short v[4]; };

__device__ __forceinline__ float bf2f(unsigned short u) {
  unsigned int x = ((unsigned int)u) << 16;
  return __builtin_bit_cast(float, x);
}
__device__ __forceinline__ unsigned short f2bf(float f) {
  unsigned int u = __builtin_bit_cast(unsigned int, f);
  u += 0x7fff + ((u >> 16) & 1);            // round-to-nearest-even
  return (unsigned short)(u >> 16);
}

// C[b][m][pix] = sum_k A[m][k] * B[b][k][pix] + bias[m]
// A: [256][KDIM] fp32 row-major. Bsrc: [16][KDIM][4096], fp32 (GEMM1) or bf16 (GEMM2).
// grid = 512 (16 b x 32 pixel-tiles of 128), block = 512 (8 waves), tile 256x128.
template<int KDIM, bool B_BF16, bool DO_CTX, bool DO_BN>
__global__ __launch_bounds__(512)
void gemm_kernel(const float* __restrict__ A, const void* __restrict__ Bsrc,
                 const float* __restrict__ bias, unsigned short* __restrict__ Cout,
                 float* __restrict__ ctx_sum, float* __restrict__ bn_sums)
{
  __shared__ unsigned short A_sh[256 * 64];   // [m][k] bf16, XOR-swizzled
  __shared__ unsigned short B_sh[128 * 64];   // [pix][k] bf16, XOR-swizzled
  __shared__ float ctx_lds[1024];
  __shared__ float bn_lds[512];

  const int tid  = threadIdx.x;
  const int lane = tid & 63;
  const int wv   = tid >> 6;
  const int wm   = wv >> 1, wn = wv & 1;      // wave grid 4(M) x 2(N), wave tile 64x64
  const int lr   = lane & 15, lg = lane >> 4;

  const int blk  = blockIdx.x;
  const int b    = blk >> 5;
  const int pix0 = (blk & 31) << 7;

  if (DO_CTX) { for (int i = tid; i < 1024; i += 512) ctx_lds[i] = 0.f; }
  if (DO_BN)  { if (tid < 512) bn_lds[tid] = 0.f; }
  if (DO_CTX || DO_BN) __syncthreads();

  f32x4 acc[4][4] = {};
  const int c4 = tid & 15, q = tid >> 4;

  for (int kt = 0; kt < KDIM / 64; ++kt) {
    const int kbase = kt * 64;
    // ---- stage A: 256x64 fp32 -> bf16, [m][k]
    #pragma unroll
    for (int i = 0; i < 8; ++i) {
      int f = i * 512 + tid;
      int m = f >> 4, kq = f & 15;
      f4 v = *(const f4*)(A + (size_t)m * KDIM + kbase + kq * 4);
      us4 w = { f2bf(v.v[0]), f2bf(v.v[1]), f2bf(v.v[2]), f2bf(v.v[3]) };
      int byte = m * 128 + ((kq * 8) ^ ((m & 7) << 4));
      *(us4*)((char*)A_sh + byte) = w;
    }
    // ---- stage B: 64(k) x 128(pix), transpose into [pix][k]
    if (!B_BF16) {
      const float* xb = (const float*)Bsrc;
      f4 rv[4];
      #pragma unroll
      for (int i = 0; i < 4; ++i) {
        int c = kbase + 4 * c4 + i;
        rv[i] = *(const f4*)(xb + ((size_t)b * KDIM + c) * HW + pix0 + 4 * q);
      }
      if (DO_CTX) {   // fused context-pool partial sums (each x element staged once)
        #pragma unroll
        for (int i = 0; i < 4; ++i) {
          float s = rv[i].v[0] + rv[i].v[1] + rv[i].v[2] + rv[i].v[3];
          s += __shfl_xor(s, 16, 64);
          s += __shfl_xor(s, 32, 64);
          if (lane < 16) atomicAdd(&ctx_lds[kbase + 4 * c4 + i], s);
        }
      }
      #pragma unroll
      for (int j = 0; j < 4; ++j) {
        int pix = 4 * q + j;
        us4 w = { f2bf(rv[0].v[j]), f2bf(rv[1].v[j]), f2bf(rv[2].v[j]), f2bf(rv[3].v[j]) };
        int byte = pix * 128 + ((8 * c4) ^ ((pix & 7) << 4));
        *(us4*)((char*)B_sh + byte) = w;
      }
    } else {
      const unsigned short* db = (const unsigned short*)Bsrc;
      us4 rv[4];
      #pragma unroll
      for (int i = 0; i < 4; ++i) {
        int c = kbase + 4 * c4 + i;
        rv[i] = *(const us4*)(db + ((size_t)b * KDIM + c) * HW + pix0 + 4 * q);
      }
      #pragma unroll
      for (int j = 0; j < 4; ++j) {
        int pix = 4 * q + j;
        us4 w = { rv[0].v[j], rv[1].v[j], rv[2].v[j], rv[3].v[j] };
        int byte = pix * 128 + ((8 * c4) ^ ((pix & 7) << 4));
        *(us4*)((char*)B_sh + byte) = w;
      }
    }
    __syncthreads();
    // ---- compute: 2 x 16 MFMA per wave per K-step
    #pragma unroll
    for (int kk = 0; kk < 2; ++kk) {
      bf16x8 af[4], bfr[4];
      #pragma unroll
      for (int mi = 0; mi < 4; ++mi) {
        int row  = wm * 64 + mi * 16 + lr;
        int byte = row * 128 + ((((kk << 2) | lg) ^ (row & 7)) << 4);
        af[mi] = *(const bf16x8*)((const char*)A_sh + byte);
      }
      #pragma unroll
      for (int ni = 0; ni < 4; ++ni) {
        int pr   = wn * 64 + ni * 16 + lr;
        int byte = pr * 128 + ((((kk << 2) | lg) ^ (pr & 7)) << 4);
        bfr[ni] = *(const bf16x8*)((const char*)B_sh + byte);
      }
      #pragma unroll
      for (int mi = 0; mi < 4; ++mi)
        #pragma unroll
        for (int ni = 0; ni < 4; ++ni)
          acc[mi][ni] = __builtin_amdgcn_mfma_f32_16x16x32_bf16(af[mi], bfr[ni], acc[mi][ni], 0, 0, 0);
    }
    __syncthreads();
  }

  // ---- epilogue: bias, bf16 store, optional BN partial stats
  #pragma unroll
  for (int mi = 0; mi < 4; ++mi) {
    #pragma unroll
    for (int r = 0; r < 4; ++r) {
      int o = wm * 64 + mi * 16 + lg * 4 + r;   // C/D: col=lane&15, row=(lane>>4)*4+reg
      float bo = bias[o];
      #pragma unroll
      for (int ni = 0; ni < 4; ++ni) {
        int pix = pix0 + wn * 64 + ni * 16 + lr;
        float val = acc[mi][ni][r] + bo;
        Cout[((size_t)(b * HID + o)) * HW + pix] = f2bf(val);
        if (DO_BN) {
          float s = val, s2 = val * val;
          #pragma unroll
          for (int msk = 1; msk < 16; msk <<= 1) {
            s  += __shfl_xor(s,  msk, 64);
            s2 += __shfl_xor(s2, msk, 64);
          }
          if (lr == 0) { atomicAdd(&bn_lds[o], s); atomicAdd(&bn_lds[256 + o], s2); }
        }
      }
    }
  }
  if (DO_CTX || DO_BN) __syncthreads();
  if (DO_CTX) {
    for (int e = tid; e < 1024; e += 512)
      atomicAdd(&ctx_sum[(size_t)b * 1024 + e], ctx_lds[e]);
  }
  if (DO_BN) {
    if (tid < 512) atomicAdd(&bn_sums[tid], bn_lds[tid]);
  }
}

// wave-per-output FC layer: out[b][o] = act(scale * dot(in[b][:], w[o][:]) + bias[o])
// grid: (16*N/4) blocks of 256 (4 waves); wave -> one (b,o) pair.
template<int K, int N, bool RELU>
__global__ __launch_bounds__(256)
void fc_kernel(const float* __restrict__ in, const float* __restrict__ w,
               const float* __restrict__ bias, float* __restrict__ out, float scale)
{
  const int wid  = (blockIdx.x << 2) | (threadIdx.x >> 6);
  const int lane = threadIdx.x & 63;
  const int b = wid / N, o = wid - b * N;
  const float* ip = in + (size_t)b * K;
  const float* wp = w  + (size_t)o * K;
  float p = 0.f;
  #pragma unroll
  for (int k = 0; k < K / 64; ++k) p += ip[lane + k * 64] * wp[lane + k * 64];
  #pragma unroll
  for (int m = 1; m < 64; m <<= 1) p += __shfl_xor(p, m, 64);
  if (lane == 0) {
    float v = p * scale + bias[o];
    out[(size_t)b * N + o] = RELU ? fmaxf(v, 0.f) : v;
  }
}

// per-sample per-group depthwise 3x3, padding=1 (cross-correlation, no flip)
__global__ __launch_bounds__(256)
void dwconv_kernel(const unsigned short* __restrict__ xt, const float* __restrict__ kern,
                   unsigned short* __restrict__ dw)
{
  const int b  = blockIdx.x >> 8;
  const int ch = blockIdx.x & 255;
  const int g  = ch >> 5;                      // CPG = 32
  __shared__ float kf[9];
  if (threadIdx.x < 9) kf[threadIdx.x] = kern[b * 72 + g * 9 + threadIdx.x];
  __syncthreads();
  const unsigned short* xp = xt + ((size_t)(b * HID + ch) << 12);
  unsigned short*       dp = dw + ((size_t)(b * HID + ch) << 12);
  #pragma unroll 4
  for (int i = 0; i < 16; ++i) {
    int p = (i << 8) + threadIdx.x;
    int h = p >> 6, wc = p & 63;
    float a = 0.f;
    #pragma unroll
    for (int ky = 0; ky < 3; ++ky) {
      int hh = h + ky - 1;
      if ((unsigned)hh < 64u) {
        #pragma unroll
        for (int kx = 0; kx < 3; ++kx) {
          int ww = wc + kx - 1;
          float xv = ((unsigned)ww < 64u) ? bf2f(xp[(hh << 6) + ww]) : 0.f;
          a += xv * kf[ky * 3 + kx];
        }
      }
    }
    dp[p] = f2bf(a);
  }
}

__global__ void bn_finalize_kernel(const float* __restrict__ bn_sums,
                                   const float* __restrict__ gamma, const float* __restrict__ beta,
                                   float* __restrict__ scale, float* __restrict__ shift)
{
  int t = threadIdx.x;
  if (t < 256) {
    const float inv_n = 1.f / 65536.f;          // B*H*W
    float m  = bn_sums[t] * inv_n;
    float v  = bn_sums[256 + t] * inv_n - m * m;
    float sc = gamma[t] * rsqrtf(v + 1e-5f);
    scale[t] = sc;
    shift[t] = beta[t] - m * sc;
  }
}

// out = xt + scale[o]*out_trans + shift[o]   (fp32 store)
__global__ __launch_bounds__(256)
void final_kernel(const unsigned short* __restrict__ xt, const unsigned short* __restrict__ ot,
                  const float* __restrict__ scale, const float* __restrict__ shift,
                  float* __restrict__ out)
{
  int g = blockIdx.x * 256 + threadIdx.x;       // group of 4 elements
  const int stride = 4096 * 256;
  #pragma unroll
  for (int it = 0; it < 4; ++it, g += stride) {
    int o = (g >> 10) & 255;
    us4 a = ((const us4*)xt)[g];
    us4 c = ((const us4*)ot)[g];
    float s = scale[o], h = shift[o];
    f4 r;
    #pragma unroll
    for (int j = 0; j < 4; ++j) r.v[j] = bf2f(a.v[j]) + s * bf2f(c.v[j]) + h;
    *(f4*)(out + (size_t)g * 4) = r;
  }
}

extern "C" void kernel_launch(void* const* d_in, const int* in_sizes, int n_in,
                              void* d_out, int out_size, void* d_ws, size_t ws_size,
                              hipStream_t stream)
{
  const float* x     = (const float*)d_in[0];
  const float* ctx_w = (const float*)d_in[1];
  const float* ctx_b = (const float*)d_in[2];
  const float* kg_w1 = (const float*)d_in[3];
  const float* kg_b1 = (const float*)d_in[4];
  const float* kg_w2 = (const float*)d_in[5];
  const float* kg_b2 = (const float*)d_in[6];
  const float* in_w  = (const float*)d_in[7];
  const float* in_b  = (const float*)d_in[8];
  const float* out_w = (const float*)d_in[9];
  const float* out_b = (const float*)d_in[10];
  const float* gamma = (const float*)d_in[11];
  const float* beta  = (const float*)d_in[12];
  float* out = (float*)d_out;

  char* ws = (char*)d_ws;
  unsigned short* xt  = (unsigned short*)ws;                 // 32 MiB bf16 xt
  unsigned short* dwb = (unsigned short*)(ws + 33554432);    // 32 MiB bf16 dw, aliased by out_trans
  float* ctx_sum = (float*)(ws + 67108864);                  // [16][1024]
  float* bn_sums = ctx_sum + 16384;                          // [512] (sum | sumsq)
  float* kern    = bn_sums + 512;                            // [16][72]
  float* scale   = kern + 1152;                              // [256]
  float* shift   = scale + 256;                              // [256]
  float* ctxbuf  = shift + 256;                              // [16][256]
  float* hddnbuf = ctxbuf + 4096;                            // [16][512]

  hipMemsetAsync(ctx_sum, 0, (16384 + 512) * sizeof(float), stream);

  gemm_kernel<1024, false, true,  false><<<512, 512, 0, stream>>>(in_w,  x,   in_b,  xt,  ctx_sum, nullptr);
  fc_kernel<1024, 256, true ><<<1024, 256, 0, stream>>>(ctx_sum, ctx_w, ctx_b, ctxbuf, 1.f / 4096.f);
  fc_kernel< 256, 512, true ><<<2048, 256, 0, stream>>>(ctxbuf,  kg_w1, kg_b1, hddnbuf, 1.f);
  fc_kernel< 512,  72, false><<< 288, 256, 0, stream>>>(hddnbuf, kg_w2, kg_b2, kern,    1.f);
  dwconv_kernel<<<4096, 256, 0, stream>>>(xt, kern, dwb);
  gemm_kernel<256,  true,  false, true ><<<512, 512, 0, stream>>>(out_w, dwb, out_b, dwb, nullptr, bn_sums);
  bn_finalize_kernel<<<1, 256, 0, stream>>>(bn_sums, gamma, beta, scale, shift);
  final_kernel<<<4096, 256, 0, stream>>>(xt, dwb, scale, shift, out);
}

// Round 3
// 250.076 us; speedup vs baseline: 1.7618x; 1.1561x over previous
//
#include <hip/hip_runtime.h>

#define BATCH 16
#define CIN   1024
#define HID   256
#define HW    4096

typedef __attribute__((ext_vector_type(8))) short bf16x8;
typedef __attribute__((ext_vector_type(4))) float f32x4;

struct __align__(16) f4  { float v[4]; };
struct __align__(8)  us4 { unsigned short v[4]; };

__device__ __forceinline__ float bf2f(unsigned short u) {
  unsigned int x = ((unsigned int)u) << 16;
  return __builtin_bit_cast(float, x);
}
__device__ __forceinline__ unsigned short f2bf(float f) {
  unsigned int u = __builtin_bit_cast(unsigned int, f);
  u += 0x7fff + ((u >> 16) & 1);            // round-to-nearest-even
  return (unsigned short)(u >> 16);
}

// direct-to-LDS 16B DMA: LDS dest = wave-uniform base + lane*16, global src per-lane
#define GLOAD_LDS16(g, l) \
  __builtin_amdgcn_global_load_lds((const __attribute__((address_space(1))) unsigned int*)(const void*)(g), \
                                   (__attribute__((address_space(3))) unsigned int*)(void*)(l), 16, 0, 0)

// Pre-convert fp32 [256][KD] weight matrices into bf16 K-tile images laid out
// EXACTLY as the GEMM's A_sh LDS buffer expects (XOR-swizzle pre-applied), so the
// GEMM can stage A with global_load_lds (linear DMA). Tile kt: 32 KiB.
// byte(kt,m,kq) = kt*32768 + m*128 + (((kq>>1)^(m&7))<<4 | (kq&1)<<3), kq = k-quad 0..15
__global__ __launch_bounds__(256)
void prep_kernel(const float* __restrict__ A1, unsigned short* __restrict__ O1,
                 const float* __restrict__ A2, unsigned short* __restrict__ O2)
{
  const int bidx = blockIdx.x;
  const float* A = (bidx < 256) ? A1 : A2;
  unsigned short* O = (bidx < 256) ? O1 : O2;
  const int shift = (bidx < 256) ? 8 : 6;              // quads per row: 256 | 64
  const int f = ((bidx < 256) ? bidx : bidx - 256) * 256 + threadIdx.x;
  const int m = f >> shift, kq4 = f & ((1 << shift) - 1);
  const int kt = kq4 >> 4, kq = kq4 & 15;
  f4 v = *(const f4*)(A + (((size_t)m << shift) + kq4) * 4);
  us4 w = { f2bf(v.v[0]), f2bf(v.v[1]), f2bf(v.v[2]), f2bf(v.v[3]) };
  int byte = kt * 32768 + m * 128 + ((((kq >> 1) ^ (m & 7)) << 4) | ((kq & 1) << 3));
  *(us4*)((char*)O + byte) = w;
}

// C[b][m][pix] = sum_k A[m][k]*B[b][k][pix] + bias[m]
// Aswz: pre-swizzled bf16 tile stream (from prep_kernel). Bsrc: [16][KDIM][4096] fp32|bf16.
// grid = 512 (16 b x 32 pixel-tiles of 128), block = 512 (8 waves), tile 256x128.
template<int KDIM, bool B_BF16, bool DO_CTX, bool DO_BN>
__global__ __launch_bounds__(512, 4)
void gemm_kernel(const unsigned short* __restrict__ Aswz, const void* __restrict__ Bsrc,
                 const float* __restrict__ bias, unsigned short* __restrict__ Cout,
                 float* __restrict__ ctx_sum, float* __restrict__ bn_sums)
{
  constexpr int NT = KDIM / 64;
  __shared__ unsigned short A_sh[256 * 64];   // [m][k] bf16, XOR-swizzled (DMA'd linear)
  __shared__ unsigned short B_sh[128 * 64];   // [pix][k] bf16, XOR-swizzled
  __shared__ float ctx_lds[1024];
  __shared__ float bn_lds[512];

  const int tid  = threadIdx.x;
  const int lane = tid & 63;
  const int wv   = tid >> 6;
  const int wm   = wv >> 1, wn = wv & 1;      // wave grid 4(M) x 2(N), wave tile 64x64
  const int lr   = lane & 15, lg = lane >> 4;

  const int blk  = blockIdx.x;
  const int b    = blk >> 5;
  const int pix0 = (blk & 31) << 7;

  if (DO_CTX) { for (int i = tid; i < 1024; i += 512) ctx_lds[i] = 0.f; }
  if (DO_BN)  { if (tid < 512) bn_lds[tid] = 0.f; }
  if (DO_CTX || DO_BN) __syncthreads();

  f32x4 acc[4][4] = {};
  const int c4 = tid & 15, q = tid >> 4;      // B staging: thread -> 4 c-rows x 4 pixels

  const float*          xb = (const float*)Bsrc;
  const unsigned short* db = (const unsigned short*)Bsrc;

  // ---- prologue: load B tile kt=0 into regs
  f4  curf[4];
  us4 curh[4];
  if (!B_BF16) {
    #pragma unroll
    for (int i = 0; i < 4; ++i)
      curf[i] = *(const f4*)(xb + ((size_t)b * KDIM + 4 * c4 + i) * HW + pix0 + 4 * q);
  } else {
    #pragma unroll
    for (int i = 0; i < 4; ++i)
      curh[i] = *(const us4*)(db + ((size_t)b * KDIM + 4 * c4 + i) * HW + pix0 + 4 * q);
  }

  for (int kt = 0; kt < NT; ++kt) {
    // ---- stage A: 4x 16B DMA per thread, pre-swizzled source, linear LDS
    {
      const char* asrc = (const char*)Aswz + kt * 32768 + wv * 1024 + lane * 16;
      char*       adst = (char*)A_sh + wv * 1024;
      GLOAD_LDS16(asrc,         adst);
      GLOAD_LDS16(asrc +  8192, adst +  8192);
      GLOAD_LDS16(asrc + 16384, adst + 16384);
      GLOAD_LDS16(asrc + 24576, adst + 24576);
    }
    // ---- stage B from cur regs: transpose 4c x 4pix, fp32->bf16
    if (!B_BF16) {
      if (DO_CTX) {   // fused context-pool partial sums (each x element staged once)
        #pragma unroll
        for (int i = 0; i < 4; ++i) {
          float s = curf[i].v[0] + curf[i].v[1] + curf[i].v[2] + curf[i].v[3];
          s += __shfl_xor(s, 16, 64);
          s += __shfl_xor(s, 32, 64);
          if (lane < 16) atomicAdd(&ctx_lds[kt * 64 + 4 * c4 + i], s);
        }
      }
      #pragma unroll
      for (int j = 0; j < 4; ++j) {
        int pix = 4 * q + j;
        us4 w = { f2bf(curf[0].v[j]), f2bf(curf[1].v[j]), f2bf(curf[2].v[j]), f2bf(curf[3].v[j]) };
        *(us4*)((char*)B_sh + pix * 128 + ((8 * c4) ^ ((pix & 7) << 4))) = w;
      }
    } else {
      #pragma unroll
      for (int j = 0; j < 4; ++j) {
        int pix = 4 * q + j;
        us4 w = { curh[0].v[j], curh[1].v[j], curh[2].v[j], curh[3].v[j] };
        *(us4*)((char*)B_sh + pix * 128 + ((8 * c4) ^ ((pix & 7) << 4))) = w;
      }
    }
    __syncthreads();   // drains A DMA (vmcnt) + B ds_writes (lgkm)

    // ---- T14: issue next B-tile loads now; vmcnt wait lands at next staging
    if (kt + 1 < NT) {
      const int kb = (kt + 1) * 64;
      if (!B_BF16) {
        #pragma unroll
        for (int i = 0; i < 4; ++i)
          curf[i] = *(const f4*)(xb + ((size_t)b * KDIM + kb + 4 * c4 + i) * HW + pix0 + 4 * q);
      } else {
        #pragma unroll
        for (int i = 0; i < 4; ++i)
          curh[i] = *(const us4*)(db + ((size_t)b * KDIM + kb + 4 * c4 + i) * HW + pix0 + 4 * q);
      }
    }
    __builtin_amdgcn_sched_barrier(0);

    // ---- compute: 2 x 16 MFMA per wave
    #pragma unroll
    for (int kk = 0; kk < 2; ++kk) {
      bf16x8 af[4], bfr[4];
      #pragma unroll
      for (int mi = 0; mi < 4; ++mi) {
        int row  = wm * 64 + mi * 16 + lr;
        af[mi] = *(const bf16x8*)((const char*)A_sh + row * 128 + ((((kk << 2) | lg) ^ (row & 7)) << 4));
      }
      #pragma unroll
      for (int ni = 0; ni < 4; ++ni) {
        int pr   = wn * 64 + ni * 16 + lr;
        bfr[ni] = *(const bf16x8*)((const char*)B_sh + pr * 128 + ((((kk << 2) | lg) ^ (pr & 7)) << 4));
      }
      #pragma unroll
      for (int mi = 0; mi < 4; ++mi)
        #pragma unroll
        for (int ni = 0; ni < 4; ++ni)
          acc[mi][ni] = __builtin_amdgcn_mfma_f32_16x16x32_bf16(af[mi], bfr[ni], acc[mi][ni], 0, 0, 0);
    }

    // ---- light barrier: drain LDS reads only; B-prefetch stays in flight (T4)
    __builtin_amdgcn_sched_barrier(0);
    asm volatile("s_waitcnt lgkmcnt(0)" ::: "memory");
    __builtin_amdgcn_sched_barrier(0);
    __builtin_amdgcn_s_barrier();
  }

  // ---- epilogue: bias, bf16 store, optional BN partial stats
  #pragma unroll
  for (int mi = 0; mi < 4; ++mi) {
    #pragma unroll
    for (int r = 0; r < 4; ++r) {
      int o = wm * 64 + mi * 16 + lg * 4 + r;   // C/D: col=lane&15, row=(lane>>4)*4+reg
      float bo = bias[o];
      #pragma unroll
      for (int ni = 0; ni < 4; ++ni) {
        int pix = pix0 + wn * 64 + ni * 16 + lr;
        float val = acc[mi][ni][r] + bo;
        Cout[((size_t)(b * HID + o)) * HW + pix] = f2bf(val);
        if (DO_BN) {
          float s = val, s2 = val * val;
          #pragma unroll
          for (int msk = 1; msk < 16; msk <<= 1) {
            s  += __shfl_xor(s,  msk, 64);
            s2 += __shfl_xor(s2, msk, 64);
          }
          if (lr == 0) { atomicAdd(&bn_lds[o], s); atomicAdd(&bn_lds[256 + o], s2); }
        }
      }
    }
  }
  if (DO_CTX || DO_BN) __syncthreads();
  if (DO_CTX) {
    for (int e = tid; e < 1024; e += 512)
      atomicAdd(&ctx_sum[(size_t)b * 1024 + e], ctx_lds[e]);
  }
  if (DO_BN) {
    if (tid < 512) atomicAdd(&bn_sums[tid], bn_lds[tid]);
  }
}

// wave-per-output FC layer: out[b][o] = act(scale * dot(in[b][:], w[o][:]) + bias[o])
template<int K, int N, bool RELU>
__global__ __launch_bounds__(256)
void fc_kernel(const float* __restrict__ in, const float* __restrict__ w,
               const float* __restrict__ bias, float* __restrict__ out, float scale)
{
  const int wid  = (blockIdx.x << 2) | (threadIdx.x >> 6);
  const int lane = threadIdx.x & 63;
  const int b = wid / N, o = wid - b * N;
  const float* ip = in + (size_t)b * K;
  const float* wp = w  + (size_t)o * K;
  float p = 0.f;
  #pragma unroll
  for (int k = 0; k < K / 64; ++k) p += ip[lane + k * 64] * wp[lane + k * 64];
  #pragma unroll
  for (int m = 1; m < 64; m <<= 1) p += __shfl_xor(p, m, 64);
  if (lane == 0) {
    float v = p * scale + bias[o];
    out[(size_t)b * N + o] = RELU ? fmaxf(v, 0.f) : v;
  }
}

// per-sample per-group depthwise 3x3, padding=1 (cross-correlation, no flip)
__global__ __launch_bounds__(256)
void dwconv_kernel(const unsigned short* __restrict__ xt, const float* __restrict__ kern,
                   unsigned short* __restrict__ dw)
{
  const int b  = blockIdx.x >> 8;
  const int ch = blockIdx.x & 255;
  const int g  = ch >> 5;                      // CPG = 32
  __shared__ float kf[9];
  if (threadIdx.x < 9) kf[threadIdx.x] = kern[b * 72 + g * 9 + threadIdx.x];
  __syncthreads();
  const unsigned short* xp = xt + ((size_t)(b * HID + ch) << 12);
  unsigned short*       dp = dw + ((size_t)(b * HID + ch) << 12);
  #pragma unroll 4
  for (int i = 0; i < 16; ++i) {
    int p = (i << 8) + threadIdx.x;
    int h = p >> 6, wc = p & 63;
    float a = 0.f;
    #pragma unroll
    for (int ky = 0; ky < 3; ++ky) {
      int hh = h + ky - 1;
      if ((unsigned)hh < 64u) {
        #pragma unroll
        for (int kx = 0; kx < 3; ++kx) {
          int ww = wc + kx - 1;
          float xv = ((unsigned)ww < 64u) ? bf2f(xp[(hh << 6) + ww]) : 0.f;
          a += xv * kf[ky * 3 + kx];
        }
      }
    }
    dp[p] = f2bf(a);
  }
}

__global__ void bn_finalize_kernel(const float* __restrict__ bn_sums,
                                   const float* __restrict__ gamma, const float* __restrict__ beta,
                                   float* __restrict__ scale, float* __restrict__ shift)
{
  int t = threadIdx.x;
  if (t < 256) {
    const float inv_n = 1.f / 65536.f;          // B*H*W
    float m  = bn_sums[t] * inv_n;
    float v  = bn_sums[256 + t] * inv_n - m * m;
    float sc = gamma[t] * rsqrtf(v + 1e-5f);
    scale[t] = sc;
    shift[t] = beta[t] - m * sc;
  }
}

// out = xt + scale[o]*out_trans + shift[o]   (fp32 store)
__global__ __launch_bounds__(256)
void final_kernel(const unsigned short* __restrict__ xt, const unsigned short* __restrict__ ot,
                  const float* __restrict__ scale, const float* __restrict__ shift,
                  float* __restrict__ out)
{
  int g = blockIdx.x * 256 + threadIdx.x;       // group of 4 elements
  const int stride = 4096 * 256;
  #pragma unroll
  for (int it = 0; it < 4; ++it, g += stride) {
    int o = (g >> 10) & 255;
    us4 a = ((const us4*)xt)[g];
    us4 c = ((const us4*)ot)[g];
    float s = scale[o], h = shift[o];
    f4 r;
    #pragma unroll
    for (int j = 0; j < 4; ++j) r.v[j] = bf2f(a.v[j]) + s * bf2f(c.v[j]) + h;
    *(f4*)(out + (size_t)g * 4) = r;
  }
}

extern "C" void kernel_launch(void* const* d_in, const int* in_sizes, int n_in,
                              void* d_out, int out_size, void* d_ws, size_t ws_size,
                              hipStream_t stream)
{
  const float* x     = (const float*)d_in[0];
  const float* ctx_w = (const float*)d_in[1];
  const float* ctx_b = (const float*)d_in[2];
  const float* kg_w1 = (const float*)d_in[3];
  const float* kg_b1 = (const float*)d_in[4];
  const float* kg_w2 = (const float*)d_in[5];
  const float* kg_b2 = (const float*)d_in[6];
  const float* in_w  = (const float*)d_in[7];
  const float* in_b  = (const float*)d_in[8];
  const float* out_w = (const float*)d_in[9];
  const float* out_b = (const float*)d_in[10];
  const float* gamma = (const float*)d_in[11];
  const float* beta  = (const float*)d_in[12];
  float* out = (float*)d_out;

  char* ws = (char*)d_ws;
  unsigned short* xt  = (unsigned short*)ws;                 // 32 MiB bf16 xt
  unsigned short* dwb = (unsigned short*)(ws + 33554432);    // 32 MiB bf16 dw, aliased by out_trans
  float* ctx_sum = (float*)(ws + 67108864);                  // [16][1024]
  float* bn_sums = ctx_sum + 16384;                          // [512] (sum | sumsq)
  float* kern    = bn_sums + 512;                            // [16][72]
  float* scale   = kern + 1152;                              // [256]
  float* shift   = scale + 256;                              // [256]
  float* ctxbuf  = shift + 256;                              // [16][256]
  float* hddnbuf = ctxbuf + 4096;                            // [16][512]
  unsigned short* aswz1 = (unsigned short*)(ws + 67108864 + 131072);  // 512 KiB (in_w bf16 swz)
  unsigned short* aswz2 = (unsigned short*)(ws + 67108864 + 131072 + 524288); // 128 KiB (out_w)

  hipMemsetAsync(ctx_sum, 0, (16384 + 512) * sizeof(float), stream);

  prep_kernel<<<320, 256, 0, stream>>>(in_w, aswz1, out_w, aswz2);
  gemm_kernel<1024, false, true,  false><<<512, 512, 0, stream>>>(aswz1, x,   in_b,  xt,  ctx_sum, nullptr);
  fc_kernel<1024, 256, true ><<<1024, 256, 0, stream>>>(ctx_sum, ctx_w, ctx_b, ctxbuf, 1.f / 4096.f);
  fc_kernel< 256, 512, true ><<<2048, 256, 0, stream>>>(ctxbuf,  kg_w1, kg_b1, hddnbuf, 1.f);
  fc_kernel< 512,  72, false><<< 288, 256, 0, stream>>>(hddnbuf, kg_w2, kg_b2, kern,    1.f);
  dwconv_kernel<<<4096, 256, 0, stream>>>(xt, kern, dwb);
  gemm_kernel<256,  true,  false, true ><<<512, 512, 0, stream>>>(aswz2, dwb, out_b, dwb, nullptr, bn_sums);
  bn_finalize_kernel<<<1, 256, 0, stream>>>(bn_sums, gamma, beta, scale, shift);
  final_kernel<<<4096, 256, 0, stream>>>(xt, dwb, scale, shift, out);
}